// Round 7
// baseline (146.572 us; speedup 1.0000x reference)
//
#include <hip/hip_runtime.h>
#include <stdint.h>

#define DDIM   1024
#define M_TOT  8192
#define N_ROWS 4096
#define KT32   32              // 1024 / BK=32
#define NCELL  2080            // 128x128 cells, 64x64 grid lower triangle J<=I
#define SLOT   16384           // A 128x32x2B (8KB) + B 128x32x2B (8KB)
#define NSLOT  3
#define LDS_TOTAL (NSLOT * SLOT + 64)   // 49216 B -> 3 blocks/CU

typedef __attribute__((ext_vector_type(8))) short bf16x8;
typedef __attribute__((ext_vector_type(4))) float f32x4;

__device__ __forceinline__ unsigned short f2bf(float x) {
  union { float f; uint32_t u; } v; v.f = x;
  uint32_t r = v.u + 0x7FFFu + ((v.u >> 16) & 1u);
  return (unsigned short)(r >> 16);
}

__device__ __forceinline__ void gload_lds16(const void* g, void* l) {
  __builtin_amdgcn_global_load_lds(
      (const __attribute__((address_space(1))) uint32_t*)g,
      (__attribute__((address_space(3))) uint32_t*)l, 16, 0, 0);
}

// ---------- kernel 1: row-normalize, emit bf16 z, per-row pos/align partials ----------
__global__ __launch_bounds__(256) void knorm(const float* __restrict__ p1,
                                             const float* __restrict__ p2,
                                             unsigned short* __restrict__ z,
                                             float* __restrict__ pp,
                                             float* __restrict__ ap) {
  const int r = blockIdx.x;
  const int t = threadIdx.x;
  const int lane = t & 63, w = t >> 6;
  __shared__ float red0[4], red1[4];

  const float4 a = ((const float4*)(p1 + (size_t)r * DDIM))[t];
  const float4 b = ((const float4*)(p2 + (size_t)r * DDIM))[t];
  float s1 = a.x*a.x + a.y*a.y + a.z*a.z + a.w*a.w;
  float s2 = b.x*b.x + b.y*b.y + b.z*b.z + b.w*b.w;
  for (int off = 1; off < 64; off <<= 1) { s1 += __shfl_xor(s1, off); s2 += __shfl_xor(s2, off); }
  if (lane == 0) { red0[w] = s1; red1[w] = s2; }
  __syncthreads();
  const float S1 = red0[0] + red0[1] + red0[2] + red0[3];
  const float S2 = red1[0] + red1[1] + red1[2] + red1[3];
  const float r1 = 1.0f / sqrtf(S1);
  const float r2 = 1.0f / sqrtf(S2);
  const float n1x = a.x*r1, n1y = a.y*r1, n1z = a.z*r1, n1w = a.w*r1;
  const float n2x = b.x*r2, n2y = b.y*r2, n2z = b.z*r2, n2w = b.w*r2;
  float pos = n1x*n2x + n1y*n2y + n1z*n2z + n1w*n2w;
  float al  = (n1x-n2x)*(n1x-n2x) + (n1y-n2y)*(n1y-n2y)
            + (n1z-n2z)*(n1z-n2z) + (n1w-n2w)*(n1w-n2w);
  __syncthreads();
  for (int off = 1; off < 64; off <<= 1) { pos += __shfl_xor(pos, off); al += __shfl_xor(al, off); }
  if (lane == 0) { red0[w] = pos; red1[w] = al; }
  __syncthreads();
  if (t == 0) {
    pp[r] = red0[0] + red0[1] + red0[2] + red0[3];
    ap[r] = red1[0] + red1[1] + red1[2] + red1[3];
  }
  ushort4 o1, o2;
  o1.x = f2bf(n1x); o1.y = f2bf(n1y); o1.z = f2bf(n1z); o1.w = f2bf(n1w);
  o2.x = f2bf(n2x); o2.y = f2bf(n2y); o2.z = f2bf(n2z); o2.w = f2bf(n2w);
  ((ushort4*)(z + (size_t)r * DDIM))[t] = o1;
  ((ushort4*)(z + (size_t)(r + N_ROWS) * DDIM))[t] = o2;
}

// stage one BK=32 K-tile (A 128 rows + B 128 cols, 64B/row) into ring slot.
// LDS linear, rows at 64B stride. Chunk c = 16 rows = 1024B; per wave: A chunks
// {wid, wid+4}, B chunks {wid, wid+4} -> 4 gload_lds16/wave. Dest is
// wave-uniform base + lane*16 (HW requirement); source row = lane>>2, k16 = lane&3.
__device__ __forceinline__ void stage32(const char* zb, int rowA0, int colB0,
                                        int kt, char* slot, int wid, int lane) {
  const int kb = kt * 64;
  const int rsub = lane >> 2;
  const int cb = (lane & 3) * 16;
  const int c0 = wid, c1 = wid + 4;
  gload_lds16(zb + (size_t)(rowA0 + c0 * 16 + rsub) * 2048 + kb + cb,
              slot + c0 * 1024 + lane * 16);
  gload_lds16(zb + (size_t)(rowA0 + c1 * 16 + rsub) * 2048 + kb + cb,
              slot + c1 * 1024 + lane * 16);
  gload_lds16(zb + (size_t)(colB0 + c0 * 16 + rsub) * 2048 + kb + cb,
              slot + 8192 + c0 * 1024 + lane * 16);
  gload_lds16(zb + (size_t)(colB0 + c1 * 16 + rsub) * 2048 + kb + cb,
              slot + 8192 + c1 * 1024 + lane * 16);
}

// ---------- kernel 2: persistent fused z@z^T, 128x128 cells, 3-slot ring, counted vmcnt ----------
__global__ __launch_bounds__(256, 3) void kgemm(const unsigned short* __restrict__ z,
                                                float* __restrict__ denom,
                                                float* __restrict__ scal,
                                                int* __restrict__ ctr) {
  extern __shared__ char lds[];
  float* red  = (float*)(lds + NSLOT * SLOT);
  int*  cellp = (int*)(red + 8);

  const int tid  = threadIdx.x;
  const int lane = tid & 63, wid = tid >> 6;
  const int wsr  = wid >> 1, wsc = wid & 1;   // 2x2 waves, wave tile 64x64
  const int lr = lane >> 4, lc = lane & 15;
  const char* zb = (const char*)z;
  const float RK10 = 14.426950408889634f;  // 10 * log2(e)
  const float K4   = 5.770780163555856f;   // 4 * log2(e)

  while (true) {
    __syncthreads();
    if (tid == 0) *cellp = atomicAdd(ctr, 1);
    __syncthreads();
    const int cell = *cellp;
    if (cell >= NCELL) break;

    int I = (int)((sqrtf(8.0f * (float)cell + 1.0f) - 1.0f) * 0.5f);
    while ((I + 1) * (I + 2) / 2 <= cell) ++I;
    while (I * (I + 1) / 2 > cell) --I;
    const int J = cell - I * (I + 1) / 2;
    const int rowA0 = I * 128, colB0 = J * 128;
    // wave-uniform: any strict-lower element in this wave's 64x64 quadrant?
    const bool useful = (colB0 + wsc * 64) < (rowA0 + wsr * 64 + 64);

    f32x4 acc[4][4] = {};
    stage32(zb, rowA0, colB0, 0, lds, wid, lane);
    stage32(zb, rowA0, colB0, 1, lds + SLOT, wid, lane);
    asm volatile("s_waitcnt vmcnt(4)" ::: "memory");
    __builtin_amdgcn_s_barrier();
    __builtin_amdgcn_sched_barrier(0);

    for (int t = 0; t < KT32; ++t) {
      if (t + 2 < KT32)
        stage32(zb, rowA0, colB0, t + 2, lds + ((t + 2) % 3) * SLOT, wid, lane);
      __builtin_amdgcn_sched_barrier(0);
      const char* S = lds + (t % 3) * SLOT;
      if (useful) {
        bf16x8 af[4], bg[4];
#pragma unroll
        for (int m = 0; m < 4; ++m)
          af[m] = *(const bf16x8*)(S + (wsr * 64 + m * 16 + lc) * 64 + lr * 16);
#pragma unroll
        for (int n = 0; n < 4; ++n)
          bg[n] = *(const bf16x8*)(S + 8192 + (wsc * 64 + n * 16 + lc) * 64 + lr * 16);
        __builtin_amdgcn_s_setprio(1);
#pragma unroll
        for (int m = 0; m < 4; ++m)
#pragma unroll
          for (int n = 0; n < 4; ++n)
            acc[m][n] = __builtin_amdgcn_mfma_f32_16x16x32_bf16(af[m], bg[n], acc[m][n], 0, 0, 0);
        __builtin_amdgcn_s_setprio(0);
      }
      if (t + 2 < KT32) asm volatile("s_waitcnt vmcnt(4)" ::: "memory");
      else              asm volatile("s_waitcnt vmcnt(0)" ::: "memory");
      __builtin_amdgcn_s_barrier();
      __builtin_amdgcn_sched_barrier(0);
    }

    // ---- fused epilogue: strict-lower mask, row-sums + col-sums + unif ----
    const bool unif = (I < 16) || (I < 32 && J >= 16);
    const int  uidx = (I < 16) ? 2 : 3;
    float u = 0.0f;
    if (useful) {
      float cs[4] = {0.0f, 0.0f, 0.0f, 0.0f};
#pragma unroll
      for (int m = 0; m < 4; ++m) {
        const int growb = rowA0 + wsr * 64 + m * 16 + lr * 4;
#pragma unroll
        for (int i = 0; i < 4; ++i) {
          const int grow = growb + i;
          float rs = 0.0f;
#pragma unroll
          for (int n = 0; n < 4; ++n) {
            const int gcol = colB0 + wsc * 64 + n * 16 + lc;
            const bool incl = (gcol < grow);
            float e = incl ? exp2f(acc[m][n][i] * RK10) : 0.0f;
            rs += e;
            cs[n] += e;
            if (unif) u += incl ? exp2f(acc[m][n][i] * K4 - K4) : 0.0f;
          }
          rs += __shfl_xor(rs, 1); rs += __shfl_xor(rs, 2);
          rs += __shfl_xor(rs, 4); rs += __shfl_xor(rs, 8);
          if (lc == 0 && rs > 0.0f) atomicAdd(&denom[grow], rs);
        }
      }
#pragma unroll
      for (int n = 0; n < 4; ++n) {
        float c = cs[n];
        c += __shfl_xor(c, 16); c += __shfl_xor(c, 32);
        if (lr == 0 && c > 0.0f) atomicAdd(&denom[colB0 + wsc * 64 + n * 16 + lc], c);
      }
    }
    if (unif) {
      for (int off = 1; off < 64; off <<= 1) u += __shfl_xor(u, off);
      if (lane == 0) red[wid] = u;
      __syncthreads();
      if (tid == 0) {
        const float s4 = red[0] + red[1] + red[2] + red[3];
        atomicAdd(&scal[uidx], 2.0f * s4);   // each pair once; mirror via x2
      }
    }
  }
}

// ---------- kernel 3: reduce log(denom) + pos/align partials + final combine ----------
__global__ __launch_bounds__(1024) void klogf(const float* __restrict__ denom,
                                              const float* __restrict__ pp,
                                              const float* __restrict__ ap,
                                              const float* __restrict__ scal,
                                              float* __restrict__ out) {
  __shared__ float redl[16], redp[16], reda[16];
  const int tid = threadIdx.x;
  float s = 0.0f, sp = 0.0f, sa = 0.0f;
#pragma unroll
  for (int q = 0; q < 8; ++q) s += logf(denom[q * 1024 + tid]);
#pragma unroll
  for (int q = 0; q < 4; ++q) { sp += pp[q * 1024 + tid]; sa += ap[q * 1024 + tid]; }
  const int lane = tid & 63, w = tid >> 6;
  for (int off = 1; off < 64; off <<= 1) {
    s += __shfl_xor(s, off); sp += __shfl_xor(sp, off); sa += __shfl_xor(sa, off);
  }
  if (lane == 0) { redl[w] = s; redp[w] = sp; reda[w] = sa; }
  __syncthreads();
  if (tid == 0) {
    float S = 0.0f, SP = 0.0f, SA = 0.0f;
#pragma unroll
    for (int i = 0; i < 16; ++i) { S += redl[i]; SP += redp[i]; SA += reda[i]; }
    const float P = 2048.0f * 2047.0f * 0.5f;
    out[0] = (S - 20.0f * SP) / 8192.0f;    // (sum log d - 2*sum_pos/t) / 2n
    out[1] = SA / 4096.0f;                  // lalign
    out[2] = 0.5f * (logf(scal[2] * 0.5f / P) + logf(scal[3] * 0.5f / P));
  }
}

extern "C" void kernel_launch(void* const* d_in, const int* in_sizes, int n_in,
                              void* d_out, int out_size, void* d_ws, size_t ws_size,
                              hipStream_t stream) {
  const float* p1 = (const float*)d_in[0];
  const float* p2 = (const float*)d_in[1];
  float* out = (float*)d_out;
  char* ws = (char*)d_ws;
  unsigned short* z = (unsigned short*)ws;                    // 8192 x 1024 bf16 = 16 MB
  float* denom = (float*)(ws + (size_t)M_TOT * DDIM * 2);     // 8192 f32
  float* scal  = denom + M_TOT;                               // 8 f32 [., ., U0, U1]
  int*   ctr   = (int*)(scal + 8);                            // 8 ints (work counter)
  float* pp    = (float*)(ctr + 8);                           // 4096 pos partials
  float* ap    = pp + 4096;                                   // 4096 align partials

  (void)hipFuncSetAttribute((const void*)kgemm,
                            hipFuncAttributeMaxDynamicSharedMemorySize, LDS_TOTAL);
  hipMemsetAsync(denom, 0, (M_TOT + 8) * sizeof(float) + 8 * sizeof(int), stream);
  knorm<<<N_ROWS, 256, 0, stream>>>(p1, p2, z, pp, ap);
  kgemm<<<768, 256, LDS_TOTAL, stream>>>(z, denom, scal, ctr);
  klogf<<<1, 1024, 0, stream>>>(denom, pp, ap, scal, out);
}